// Round 1
// baseline (461.635 us; speedup 1.0000x reference)
//
#include <hip/hip_runtime.h>

#define TT 200
#define NN 512
#define DD 4
#define HH 64
#define GG 192
#define LL 32
#define SB 16   // sequences per block
#define HP 20   // hT row pitch in floats (breaks pow2 bank pattern)

__device__ __forceinline__ float sigmoidf_(float x) {
    float e = __expf(-x);
    return __builtin_amdgcn_rcpf(1.0f + e);
}
__device__ __forceinline__ float tanhf_(float x) {
    float xc = fminf(fmaxf(x, -15.0f), 15.0f);
    float e = __expf(-2.0f * xc);
    return (1.0f - e) * __builtin_amdgcn_rcpf(1.0f + e);
}

__global__ __launch_bounds__(256, 1)
void gru_traj_kernel(const float* __restrict__ xg,    // (B,T,N,D)
                     const float* __restrict__ W_ih,  // (192,4)
                     const float* __restrict__ W_hh,  // (192,64)
                     const float* __restrict__ b_ih,  // (192,)
                     const float* __restrict__ b_hh,  // (192,)
                     const float* __restrict__ W_enc, // (32,64)
                     const float* __restrict__ b_enc, // (32,)
                     float* __restrict__ out)         // (B,N,32)
{
    __shared__ __align__(16) float hT[HH][HP];       // hT[k][s] : h state transposed
    __shared__ float A[SB][GG];                      // gate pre-activations
    __shared__ __align__(16) float xs[2][SB][DD];    // staged x_t (double buffered)

    const int tid = threadIdx.x;
    const int bid = blockIdx.x;
    const int b  = bid >> 5;           // bid / 32  (32 blocks per batch: 512/16)
    const int n0 = (bid & 31) << 4;    // first n of this block

    // ---- dot-phase mapping: thread = (gate triple g3, seq quarter sq) ----
    const int g3 = tid & 63;           // gates 3*g3 .. 3*g3+2
    const int sq = tid >> 6;           // seqs 4*sq .. 4*sq+3
    const int s0 = sq << 2;

    // ---- update-phase mapping: thread = (h unit uj, seq group) ----
    const int uj  = tid & 63;
    const int us0 = (tid >> 6) << 2;

    // ---- W_hh rows into registers (loop-invariant for all 200 steps) ----
    float w[3][HH];
    const float* wbase = W_hh + 3 * g3 * HH;
    #pragma unroll
    for (int i = 0; i < 3; ++i) {
        #pragma unroll
        for (int k = 0; k < HH; k += 4) {
            float4 v = *reinterpret_cast<const float4*>(wbase + i * HH + k);
            w[i][k] = v.x; w[i][k + 1] = v.y; w[i][k + 2] = v.z; w[i][k + 3] = v.w;
        }
    }
    float wih[3][DD], bih3[3], bhh3[3];
    #pragma unroll
    for (int i = 0; i < 3; ++i) {
        int g = 3 * g3 + i;
        float4 v = *reinterpret_cast<const float4*>(W_ih + g * DD);
        wih[i][0] = v.x; wih[i][1] = v.y; wih[i][2] = v.z; wih[i][3] = v.w;
        bih3[i] = b_ih[g];
        bhh3[i] = b_hh[g];
    }
    // update-phase constants: W_ih row for the n-gate of unit uj
    float4 wnv = *reinterpret_cast<const float4*>(W_ih + (2 * HH + uj) * DD);
    float  bin = b_ih[2 * HH + uj];

    // ---- init: h = 0, stage x_0 ----
    for (int idx = tid; idx < HH * HP; idx += 256) ((float*)hT)[idx] = 0.0f;
    if (tid < SB * DD) {
        int s = tid >> 2, d = tid & 3;
        xs[0][s][d] = xg[((b * TT + 0) * NN + n0 + s) * DD + d];
    }
    __syncthreads();

    for (int t = 0; t < TT; ++t) {
        // prefetch x_{t+1} into a register (latency hidden under dot phase)
        float xpre = 0.0f;
        const int pf = (tid < SB * DD) && (t + 1 < TT);
        if (pf) {
            int s = tid >> 2, d = tid & 3;
            xpre = xg[((b * TT + (t + 1)) * NN + n0 + s) * DD + d];
        }
        const int cur = t & 1, nxt = cur ^ 1;

        // ---- dot phase: acc[i][s] = b_hh + h[s] . W_hh[g] ----
        float acc[3][4];
        #pragma unroll
        for (int i = 0; i < 3; ++i) {
            #pragma unroll
            for (int s = 0; s < 4; ++s) acc[i][s] = bhh3[i];
        }
        #pragma unroll
        for (int k = 0; k < HH; ++k) {
            float4 hv = *reinterpret_cast<const float4*>(&hT[k][s0]); // broadcast read
            #pragma unroll
            for (int i = 0; i < 3; ++i) {
                acc[i][0] = fmaf(w[i][k], hv.x, acc[i][0]);
                acc[i][1] = fmaf(w[i][k], hv.y, acc[i][1]);
                acc[i][2] = fmaf(w[i][k], hv.z, acc[i][2]);
                acc[i][3] = fmaf(w[i][k], hv.w, acc[i][3]);
            }
        }
        // add input part gx (with b_ih) for r/z gates; n gates store raw gh
        #pragma unroll
        for (int s = 0; s < 4; ++s) {
            float4 xv = *reinterpret_cast<const float4*>(&xs[cur][s0 + s][0]);
            #pragma unroll
            for (int i = 0; i < 3; ++i) {
                int g = 3 * g3 + i;
                float gx = fmaf(wih[i][0], xv.x, fmaf(wih[i][1], xv.y,
                           fmaf(wih[i][2], xv.z, fmaf(wih[i][3], xv.w, bih3[i]))));
                A[s0 + s][g] = acc[i][s] + ((g < 2 * HH) ? gx : 0.0f);
            }
        }
        __syncthreads();

        // ---- update phase: each thread owns (unit uj, 4 seqs) ----
        #pragma unroll
        for (int si = 0; si < 4; ++si) {
            int s = us0 + si;
            float ar  = A[s][uj];
            float az  = A[s][HH + uj];
            float ghn = A[s][2 * HH + uj];
            float4 xv = *reinterpret_cast<const float4*>(&xs[cur][s][0]);
            float gxn = fmaf(wnv.x, xv.x, fmaf(wnv.y, xv.y,
                        fmaf(wnv.z, xv.z, fmaf(wnv.w, xv.w, bin))));
            float r = sigmoidf_(ar);
            float z = sigmoidf_(az);
            float n = tanhf_(fmaf(r, ghn, gxn));
            float ho = hT[uj][s];
            hT[uj][s] = (1.0f - z) * n + z * ho;
        }
        if (pf) {
            int s = tid >> 2, d = tid & 3;
            xs[nxt][s][d] = xpre;
        }
        __syncthreads();
    }

    // ---- epilogue: out = hT @ W_enc^T + b_enc ----
    for (int o = tid; o < SB * LL; o += 256) {
        int s = o >> 5, l = o & 31;
        float acc = b_enc[l];
        #pragma unroll
        for (int k = 0; k < HH; ++k)
            acc = fmaf(hT[k][s], W_enc[l * HH + k], acc);
        out[(bid * SB + s) * LL + l] = acc;
    }
}

extern "C" void kernel_launch(void* const* d_in, const int* in_sizes, int n_in,
                              void* d_out, int out_size, void* d_ws, size_t ws_size,
                              hipStream_t stream) {
    const float* xg    = (const float*)d_in[0];
    const float* W_ih  = (const float*)d_in[1];
    const float* W_hh  = (const float*)d_in[2];
    const float* b_ih  = (const float*)d_in[3];
    const float* b_hh  = (const float*)d_in[4];
    const float* W_enc = (const float*)d_in[5];
    const float* b_enc = (const float*)d_in[6];
    float* out = (float*)d_out;

    dim3 grid(256), block(256);
    hipLaunchKernelGGL(gru_traj_kernel, grid, block, 0, stream,
                       xg, W_ih, W_hh, b_ih, b_hh, W_enc, b_enc, out);
}

// Round 2
// 221.262 us; speedup vs baseline: 2.0864x; 2.0864x over previous
//
#include <hip/hip_runtime.h>

#define TT 200
#define NN 512
#define DD 4
#define HH 64
#define LL 32
#define SB 8                 // sequences per block
#define BPB (NN / SB)        // blocks per batch = 64
#define HPITCH 68            // floats per hs row: 16B-aligned rows, 2-way banks (free)

typedef short bf16x8 __attribute__((ext_vector_type(8)));
typedef float f32x4 __attribute__((ext_vector_type(4)));

union U8 { unsigned short s[8]; bf16x8 v; };

__device__ __forceinline__ float sigmoidf_(float x) {
    float e = __expf(-x);
    return __builtin_amdgcn_rcpf(1.0f + e);
}
__device__ __forceinline__ float tanhf_(float x) {
    float xc = fminf(fmaxf(x, -15.0f), 15.0f);
    float e = __expf(-2.0f * xc);
    return (1.0f - e) * __builtin_amdgcn_rcpf(1.0f + e);
}

// f32 -> (hi, lo) bf16 limbs by truncation: x = hi + lo + err, |err| <= 2^-16 |x|
__device__ __forceinline__ void split2(float x, unsigned short& hi, unsigned short& lo) {
    unsigned u = __float_as_uint(x);
    hi = (unsigned short)(u >> 16);
    float lf = x - __uint_as_float(u & 0xffff0000u);
    lo = (unsigned short)(__float_as_uint(lf) >> 16);
}

__global__ __launch_bounds__(256, 2)
void gru_traj_kernel(const float* __restrict__ xg,    // (B,T,N,D)
                     const float* __restrict__ W_ih,  // (192,4)
                     const float* __restrict__ W_hh,  // (192,64)
                     const float* __restrict__ b_ih,  // (192,)
                     const float* __restrict__ b_hh,  // (192,)
                     const float* __restrict__ W_enc, // (32,64)
                     const float* __restrict__ b_enc, // (32,)
                     float* __restrict__ out)         // (B,N,32)
{
    __shared__ __align__(16) float hs[16][HPITCH];    // h[s][k] (rows SB..15 stay 0)
    __shared__ __align__(16) float xs[2][SB][DD];     // staged x_t, double buffered

    const int tid = threadIdx.x;
    const int bid = blockIdx.x;
    const int b   = bid >> 6;                // bid / BPB
    const int n0  = (bid & (BPB - 1)) * SB;

    const int w  = tid >> 6;     // wave 0..3 -> gate tiles {w, w+4, w+8} = r,z,n for units 16w..16w+15
    const int l  = tid & 63;
    const int lr = l & 15;       // A-row / B-col / C-col within tile
    const int lg = l >> 4;       // k-group (A/B), row-group (C)

    // ---- B fragments: W_hh^T tiles as bf16 hi/lo limbs, resident all 200 steps ----
    // B[k][g] = W_hh[g][k]; lane holds k = kc*32 + lg*8 + j, g = tile*16 + lr
    bf16x8 bh[3][2], bl[3][2];
    #pragma unroll
    for (int i = 0; i < 3; ++i) {
        const int g = (w + 4 * i) * 16 + lr;          // = i*64 + 16*w + lr
        #pragma unroll
        for (int kc = 0; kc < 2; ++kc) {
            const float* p = W_hh + g * HH + kc * 32 + lg * 8;
            U8 uh, ul;
            #pragma unroll
            for (int j = 0; j < 8; ++j) split2(p[j], uh.s[j], ul.s[j]);
            bh[i][kc] = uh.v; bl[i][kc] = ul.v;
        }
    }
    // per-lane gate constants (unit u = 16w + lr)
    float wih[3][4], bih[3], bhh[3];
    #pragma unroll
    for (int i = 0; i < 3; ++i) {
        const int g = i * 64 + 16 * w + lr;
        wih[i][0] = W_ih[g * DD + 0]; wih[i][1] = W_ih[g * DD + 1];
        wih[i][2] = W_ih[g * DD + 2]; wih[i][3] = W_ih[g * DD + 3];
        bih[i] = b_ih[g]; bhh[i] = b_hh[g];
    }

    // ---- init: h = 0 everywhere, stage x_0 ----
    for (int idx = tid; idx < 16 * HPITCH; idx += 256) ((float*)hs)[idx] = 0.0f;
    if (tid < SB * DD)
        xs[0][tid >> 2][tid & 3] = xg[((b * TT) * NN + n0 + (tid >> 2)) * DD + (tid & 3)];
    float hreg[4] = {0.f, 0.f, 0.f, 0.f};   // h[s = lg*4+r][u = 16w+lr]
    __syncthreads();

    for (int t = 0; t < TT; ++t) {
        const int cur = t & 1, nxt = cur ^ 1;
        // prefetch x_{t+1}
        float xpre = 0.0f;
        const bool pf = (tid < SB * DD) && (t + 1 < TT);
        if (pf) xpre = xg[((b * TT + t + 1) * NN + n0 + (tid >> 2)) * DD + (tid & 3)];

        // ---- A fragments from hs: lane holds h[lr][kc*32 + lg*8 + j] ----
        bf16x8 ah[2], al[2];
        #pragma unroll
        for (int kc = 0; kc < 2; ++kc) {
            const float* hp = &hs[lr][kc * 32 + lg * 8];
            float4 v0 = *reinterpret_cast<const float4*>(hp);
            float4 v1 = *reinterpret_cast<const float4*>(hp + 4);
            U8 uh, ul;
            split2(v0.x, uh.s[0], ul.s[0]); split2(v0.y, uh.s[1], ul.s[1]);
            split2(v0.z, uh.s[2], ul.s[2]); split2(v0.w, uh.s[3], ul.s[3]);
            split2(v1.x, uh.s[4], ul.s[4]); split2(v1.y, uh.s[5], ul.s[5]);
            split2(v1.z, uh.s[6], ul.s[6]); split2(v1.w, uh.s[7], ul.s[7]);
            ah[kc] = uh.v; al[kc] = ul.v;
        }

        // ---- gh = h @ W_hh^T (+ b_hh) via split-bf16 MFMA ----
        f32x4 acc[3];
        #pragma unroll
        for (int i = 0; i < 3; ++i) { acc[i][0] = bhh[i]; acc[i][1] = bhh[i]; acc[i][2] = bhh[i]; acc[i][3] = bhh[i]; }
        #pragma unroll
        for (int i = 0; i < 3; ++i) {
            #pragma unroll
            for (int kc = 0; kc < 2; ++kc) {
                acc[i] = __builtin_amdgcn_mfma_f32_16x16x32_bf16(ah[kc], bh[i][kc], acc[i], 0, 0, 0);
                acc[i] = __builtin_amdgcn_mfma_f32_16x16x32_bf16(al[kc], bh[i][kc], acc[i], 0, 0, 0);
                acc[i] = __builtin_amdgcn_mfma_f32_16x16x32_bf16(ah[kc], bl[i][kc], acc[i], 0, 0, 0);
            }
        }

        // ---- gates + h update, fully in-register ----
        // C layout: lane holds row s = lg*4 + r (reg r), col u = 16w + lr
        float hnew[4];
        #pragma unroll
        for (int r = 0; r < 4; ++r) {
            const int s  = lg * 4 + r;
            const int sc = (s < SB) ? s : 0;
            float4 x4 = *reinterpret_cast<const float4*>(&xs[cur][sc][0]);
            float gxr = fmaf(wih[0][0], x4.x, fmaf(wih[0][1], x4.y, fmaf(wih[0][2], x4.z, fmaf(wih[0][3], x4.w, bih[0]))));
            float gxz = fmaf(wih[1][0], x4.x, fmaf(wih[1][1], x4.y, fmaf(wih[1][2], x4.z, fmaf(wih[1][3], x4.w, bih[1]))));
            float gxn = fmaf(wih[2][0], x4.x, fmaf(wih[2][1], x4.y, fmaf(wih[2][2], x4.z, fmaf(wih[2][3], x4.w, bih[2]))));
            float rg = sigmoidf_(acc[0][r] + gxr);
            float z  = sigmoidf_(acc[1][r] + gxz);
            float nn = tanhf_(fmaf(rg, acc[2][r], gxn));
            hnew[r] = fmaf(z, hreg[r] - nn, nn);    // (1-z)n + z h
        }
        __syncthreads();   // all waves done reading hs (A-frags) and xs[cur]

        #pragma unroll
        for (int r = 0; r < 4; ++r) {
            const int s = lg * 4 + r;
            if (s < SB) { hreg[r] = hnew[r]; hs[s][16 * w + lr] = hnew[r]; }
        }
        if (pf) xs[nxt][tid >> 2][tid & 3] = xpre;
        __syncthreads();   // h_{t+1} visible
    }

    // ---- epilogue: out = h @ W_enc^T + b_enc ----
    if (tid < SB * LL) {
        const int s = tid >> 5, li = tid & 31;
        float a = b_enc[li];
        #pragma unroll
        for (int k = 0; k < HH; ++k)
            a = fmaf(hs[s][k], W_enc[li * HH + k], a);
        out[(bid * SB + s) * LL + li] = a;
    }
}

extern "C" void kernel_launch(void* const* d_in, const int* in_sizes, int n_in,
                              void* d_out, int out_size, void* d_ws, size_t ws_size,
                              hipStream_t stream) {
    const float* xg    = (const float*)d_in[0];
    const float* W_ih  = (const float*)d_in[1];
    const float* W_hh  = (const float*)d_in[2];
    const float* b_ih  = (const float*)d_in[3];
    const float* b_hh  = (const float*)d_in[4];
    const float* W_enc = (const float*)d_in[5];
    const float* b_enc = (const float*)d_in[6];
    float* out = (float*)d_out;

    dim3 grid(8 * BPB), block(256);   // 512 blocks -> 2 blocks/CU
    hipLaunchKernelGGL(gru_traj_kernel, grid, block, 0, stream,
                       xg, W_ih, W_hh, b_ih, b_hh, W_enc, b_enc, out);
}

// Round 3
// 122.487 us; speedup vs baseline: 3.7688x; 1.8064x over previous
//
#include <hip/hip_runtime.h>

#define TT 200
#define NN 512
#define DD 4
#define HH 64
#define LL 32
#define SB 16                // sequences per block (fills MFMA M=16)
#define BPB (NN / SB)        // 32 blocks per batch
#define KP 72                // ushort pitch per h row: 144B = 16B-aligned, reads at bank floor

typedef short bf16x8 __attribute__((ext_vector_type(8)));
typedef float f32x4 __attribute__((ext_vector_type(4)));

union U8 { unsigned short s[8]; bf16x8 v; };

__device__ __forceinline__ float sigmoidf_(float x) {
    float e = __expf(-x);
    return __builtin_amdgcn_rcpf(1.0f + e);
}
__device__ __forceinline__ float tanhf_(float x) {
    float xc = fminf(fmaxf(x, -15.0f), 15.0f);
    float e = __expf(-2.0f * xc);
    return (1.0f - e) * __builtin_amdgcn_rcpf(1.0f + e);
}

// f32 -> (hi, lo) bf16 limbs by truncation: x = hi + lo + err, |err| <= 2^-16 |x|
__device__ __forceinline__ void split2(float x, unsigned short& hi, unsigned short& lo) {
    unsigned u = __float_as_uint(x);
    hi = (unsigned short)(u >> 16);
    float lf = x - __uint_as_float(u & 0xffff0000u);
    lo = (unsigned short)(__float_as_uint(lf) >> 16);
}

__global__ __launch_bounds__(256, 1)
void gru_traj_kernel(const float* __restrict__ xg,    // (B,T,N,D)
                     const float* __restrict__ W_ih,  // (192,4)
                     const float* __restrict__ W_hh,  // (192,64)
                     const float* __restrict__ b_ih,  // (192,)
                     const float* __restrict__ b_hh,  // (192,)
                     const float* __restrict__ W_enc, // (32,64)
                     const float* __restrict__ b_enc, // (32,)
                     float* __restrict__ out)         // (B,N,32)
{
    __shared__ __align__(16) unsigned short hhi[2][SB][KP];  // h hi-limbs, double buffered
    __shared__ __align__(16) unsigned short hlo[2][SB][KP];  // h lo-limbs
    __shared__ __align__(16) float xs[2][SB][DD];            // staged x_t
    __shared__ __align__(16) float hsf[SB][HH + 4];          // f32 h for epilogue

    const int tid = threadIdx.x;
    const int bid = blockIdx.x;
    const int b   = bid >> 5;                // bid / BPB
    const int n0  = (bid & (BPB - 1)) * SB;

    const int w  = tid >> 6;     // wave -> gate tiles {w, w+4, w+8}: r,z,n for units 16w..16w+15
    const int l  = tid & 63;
    const int lr = l & 15;       // A-row / B-col / C-col within tile
    const int lg = l >> 4;       // k-group (A/B), row-group (C)

    // ---- B fragments: W_hh^T tiles as bf16 hi/lo limbs (validated layout, round 2) ----
    bf16x8 bh[3][2], bl[3][2];
    #pragma unroll
    for (int i = 0; i < 3; ++i) {
        const int g = i * 64 + 16 * w + lr;
        #pragma unroll
        for (int kc = 0; kc < 2; ++kc) {
            const float* p = W_hh + g * HH + kc * 32 + lg * 8;
            U8 uh, ul;
            #pragma unroll
            for (int j = 0; j < 8; ++j) split2(p[j], uh.s[j], ul.s[j]);
            bh[i][kc] = uh.v; bl[i][kc] = ul.v;
        }
    }
    // per-lane gate constants (unit u = 16w + lr)
    float wih[3][4], bih[3], bhh[3];
    #pragma unroll
    for (int i = 0; i < 3; ++i) {
        const int g = i * 64 + 16 * w + lr;
        wih[i][0] = W_ih[g * DD + 0]; wih[i][1] = W_ih[g * DD + 1];
        wih[i][2] = W_ih[g * DD + 2]; wih[i][3] = W_ih[g * DD + 3];
        bih[i] = b_ih[g]; bhh[i] = b_hh[g];
    }

    // ---- init: zero limb buffers (h0 = 0), stage x_0 ----
    for (int idx = tid; idx < 2 * SB * KP / 2; idx += 256) {
        reinterpret_cast<unsigned*>(hhi)[idx] = 0u;
        reinterpret_cast<unsigned*>(hlo)[idx] = 0u;
    }
    if (tid < SB * DD)
        xs[0][tid >> 2][tid & 3] = xg[((b * TT) * NN + n0 + (tid >> 2)) * DD + (tid & 3)];
    float hreg[4] = {0.f, 0.f, 0.f, 0.f};   // h[s = lg*4+r][u = 16w+lr]
    __syncthreads();

    for (int t = 0; t < TT; ++t) {
        const int cur = t & 1, nxt = cur ^ 1;
        // prefetch x_{t+1} (latency hidden under the step)
        float xpre = 0.0f;
        const bool pf = (tid < SB * DD) && (t + 1 < TT);
        if (pf) xpre = xg[((b * TT + t + 1) * NN + n0 + (tid >> 2)) * DD + (tid & 3)];

        // ---- A fragments: direct bf16-limb loads, no conversion ----
        bf16x8 ah[2], al[2];
        #pragma unroll
        for (int kc = 0; kc < 2; ++kc) {
            ah[kc] = *reinterpret_cast<const bf16x8*>(&hhi[cur][lr][kc * 32 + lg * 8]);
            al[kc] = *reinterpret_cast<const bf16x8*>(&hlo[cur][lr][kc * 32 + lg * 8]);
        }

        // ---- gx (independent of MFMA chain -> overlaps) ----
        float gxv[3][4];
        #pragma unroll
        for (int r = 0; r < 4; ++r) {
            const int s = lg * 4 + r;
            float4 x4 = *reinterpret_cast<const float4*>(&xs[cur][s][0]);
            #pragma unroll
            for (int i = 0; i < 3; ++i)
                gxv[i][r] = fmaf(wih[i][0], x4.x, fmaf(wih[i][1], x4.y,
                            fmaf(wih[i][2], x4.z, fmaf(wih[i][3], x4.w, bih[i]))));
        }

        // ---- gh = h @ W_hh^T (+ b_hh) via split-bf16 MFMA ----
        f32x4 acc[3];
        #pragma unroll
        for (int i = 0; i < 3; ++i) { acc[i][0] = bhh[i]; acc[i][1] = bhh[i]; acc[i][2] = bhh[i]; acc[i][3] = bhh[i]; }
        #pragma unroll
        for (int i = 0; i < 3; ++i) {
            #pragma unroll
            for (int kc = 0; kc < 2; ++kc) {
                acc[i] = __builtin_amdgcn_mfma_f32_16x16x32_bf16(ah[kc], bh[i][kc], acc[i], 0, 0, 0);
                acc[i] = __builtin_amdgcn_mfma_f32_16x16x32_bf16(al[kc], bh[i][kc], acc[i], 0, 0, 0);
                acc[i] = __builtin_amdgcn_mfma_f32_16x16x32_bf16(ah[kc], bl[i][kc], acc[i], 0, 0, 0);
            }
        }

        // ---- gates + h update (all lanes valid), split at writer, store to buf[nxt] ----
        #pragma unroll
        for (int r = 0; r < 4; ++r) {
            const int s = lg * 4 + r;
            const int u = 16 * w + lr;
            float rg = sigmoidf_(acc[0][r] + gxv[0][r]);
            float z  = sigmoidf_(acc[1][r] + gxv[1][r]);
            float nn = tanhf_(fmaf(rg, acc[2][r], gxv[2][r]));
            float hn = fmaf(z, hreg[r] - nn, nn);    // (1-z)n + z h
            hreg[r] = hn;
            unsigned short hi, lo;
            split2(hn, hi, lo);
            hhi[nxt][s][u] = hi;
            hlo[nxt][s][u] = lo;
        }
        if (pf) xs[nxt][tid >> 2][tid & 3] = xpre;
        __syncthreads();   // h_{t+1} limbs + x_{t+1} visible; buf[cur] free for overwrite
    }

    // ---- epilogue: out = h @ W_enc^T + b_enc ----
    #pragma unroll
    for (int r = 0; r < 4; ++r)
        hsf[lg * 4 + r][16 * w + lr] = hreg[r];
    __syncthreads();
    for (int o = tid; o < SB * LL; o += 256) {
        const int s = o >> 5, li = o & 31;
        float a = b_enc[li];
        #pragma unroll
        for (int k = 0; k < HH; ++k)
            a = fmaf(hsf[s][k], W_enc[li * HH + k], a);
        out[(bid * SB + s) * LL + li] = a;
    }
}

extern "C" void kernel_launch(void* const* d_in, const int* in_sizes, int n_in,
                              void* d_out, int out_size, void* d_ws, size_t ws_size,
                              hipStream_t stream) {
    const float* xg    = (const float*)d_in[0];
    const float* W_ih  = (const float*)d_in[1];
    const float* W_hh  = (const float*)d_in[2];
    const float* b_ih  = (const float*)d_in[3];
    const float* b_hh  = (const float*)d_in[4];
    const float* W_enc = (const float*)d_in[5];
    const float* b_enc = (const float*)d_in[6];
    float* out = (float*)d_out;

    dim3 grid(8 * BPB), block(256);   // 256 blocks -> 1 block/CU
    hipLaunchKernelGGL(gru_traj_kernel, grid, block, 0, stream,
                       xg, W_ih, W_hh, b_ih, b_hh, W_enc, b_enc, out);
}